// Round 16
// baseline (646.866 us; speedup 1.0000x reference)
//
#include <hip/hip_runtime.h>
#include <math.h>

#define B_    64
#define CIN   64
#define COUT  128
#define HWHW  4096   // 64*64
#define NPIX  (B_ * COUT * HWHW)   // 33,554,432 per output map
#define TAU   2e-4f
#define NW3   204800               // 4 cc * 25 tap * 128 cout * 16 k
#define POOLED_FLOATS (B_ * COUT * 1024)   // 8,388,608
#define PART_FLOATS   (B_ * 10 * COUT)     // 81,920
#define PNS   66                   // pnprep LDS stride (bank-safe transpose)

typedef _Float16 half8  __attribute__((ext_vector_type(8)));
typedef _Float16 half2v __attribute__((ext_vector_type(2)));
typedef float    f32x4  __attribute__((ext_vector_type(4)));
typedef float    f32x16 __attribute__((ext_vector_type(16)));

__device__ __forceinline__ void gload_lds16(const void* g, void* l)
{
    __builtin_amdgcn_global_load_lds(
        (const __attribute__((address_space(1))) unsigned int*)g,
        (__attribute__((address_space(3))) unsigned int*)l, 16, 0, 0);
}

// ---------------------------------------------------------------------------
// Weight pre-transform: W[cout][cin][5][5] f32 ->
//   whi/wlo [cc(4)][tap(25)][cout(128)][k(16)] f16, cin = cc*16 + k.
// ---------------------------------------------------------------------------
__global__ __launch_bounds__(256) void wprep_kernel(
    const float* __restrict__ W, _Float16* __restrict__ whi,
    _Float16* __restrict__ wlo)
{
    int e = blockIdx.x * 256 + threadIdx.x;
    if (e >= NW3) return;
    int k   = e & 15;
    int co  = (e >> 4) & 127;
    int r   = e >> 11;
    int tap = r % 25;
    int cc  = r / 25;
    float w = W[(size_t)((co << 6) + (cc << 4) + k) * 25 + tap];
    _Float16 h = (_Float16)w;
    whi[e] = h;
    wlo[e] = (_Float16)(w - (float)h);
}

// ---------------------------------------------------------------------------
// P_new pre-pass: pn = a*P + (1-a)*Q (f32), split f16 hi/lo, channels-last:
//   pn[((b*64+y)*64+x)*64 + cin]
// ---------------------------------------------------------------------------
__global__ __launch_bounds__(256) void pnprep_kernel(
    const float* __restrict__ P, const float* __restrict__ Q,
    _Float16* __restrict__ pnh, _Float16* __restrict__ pnl,
    float alpha, float oma)
{
    const int tid = threadIdx.x;
    const int y   = blockIdx.x;
    const int b   = blockIdx.y;
    __shared__ _Float16 th[64 * PNS];
    __shared__ _Float16 tl[64 * PNS];

    const size_t rb = (size_t)b * CIN * HWHW + ((size_t)y << 6);
#pragma unroll
    for (int k = 0; k < 4; ++k) {
        int idx = tid + (k << 8);            // 0..1023
        int cin = idx >> 4;
        int x0  = (idx & 15) << 2;
        float4 p4 = *(const float4*)(P + rb + (size_t)cin * HWHW + x0);
        float4 q4 = *(const float4*)(Q + rb + (size_t)cin * HWHW + x0);
        float pn[4] = { alpha * p4.x + oma * q4.x, alpha * p4.y + oma * q4.y,
                        alpha * p4.z + oma * q4.z, alpha * p4.w + oma * q4.w };
        half2v h0, h1, l0, l1;
        {
            _Float16 a0 = (_Float16)pn[0], a1 = (_Float16)pn[1];
            _Float16 a2 = (_Float16)pn[2], a3 = (_Float16)pn[3];
            h0[0] = a0; h0[1] = a1; h1[0] = a2; h1[1] = a3;
            l0[0] = (_Float16)(pn[0] - (float)a0);
            l0[1] = (_Float16)(pn[1] - (float)a1);
            l1[0] = (_Float16)(pn[2] - (float)a2);
            l1[1] = (_Float16)(pn[3] - (float)a3);
        }
        int base = cin * PNS + x0;           // 4B-aligned (x0 even)
        *(half2v*)&th[base]     = h0;
        *(half2v*)&th[base + 2] = h1;
        *(half2v*)&tl[base]     = l0;
        *(half2v*)&tl[base + 2] = l1;
    }
    __syncthreads();

    const size_t ob = ((((size_t)b << 12) + ((size_t)y << 6)) << 6);  // f16 units
#pragma unroll
    for (int k = 0; k < 2; ++k) {
        int gg  = tid + (k << 8);            // 0..511
        int x   = gg >> 3;
        int oct = gg & 7;
        half8 hv, lv;
#pragma unroll
        for (int j = 0; j < 8; ++j) {
            hv[j] = th[(oct * 8 + j) * PNS + x];
            lv[j] = tl[(oct * 8 + j) * PNS + x];
        }
        *(half8*)(pnh + ob + ((size_t)x << 6) + (oct << 3)) = hv;
        *(half8*)(pnl + ob + ((size_t)x << 6) + (oct << 3)) = lv;
    }
}

// ---------------------------------------------------------------------------
// MFMA conv, round-16: REGISTER DIET for occupancy (TLP over ILP).
//  Cross-round data: VGPR 48->occ 52%, 76->32%, 92-104->21%; every ILP
//  gadget (ping-pong, prefetch) was null-to-negative while holding occ at
//  ~2 blocks/CU. This round: single weight buffer, #pragma unroll 1 tap
//  loop (no unroll register inflation), pointer-increment addressing
//  (wave-uniform scalars -> SGPR). Target: in-loop ~48 VGPR + 64 acc.
//  Keep: planar LDS, pass-major MFMA (bit-identical U), setprio, staging.
// ---------------------------------------------------------------------------
struct WFrag2 { half8 h[2]; half8 l[2]; };

__global__ __launch_bounds__(256) void lif_conv_mfma_pn_kernel(
    const _Float16* __restrict__ pnh, const _Float16* __restrict__ pnl,
    const float* __restrict__ R, const _Float16* __restrict__ whi,
    const _Float16* __restrict__ wlo, const float* __restrict__ bias,
    float* __restrict__ out, float* __restrict__ pooled,
    const void* __restrict__ zp,
    unsigned* __restrict__ cnt, int* __restrict__ list, int cap,
    float gamma)
{
    const int tid  = threadIdx.x;
    const int wave = tid >> 6;
    const int lane = tid & 63;
    const int b      = blockIdx.z;
    const int cobase = blockIdx.y << 6;          // 0 or 64
    const int ty0    = (blockIdx.x >> 2) << 4;
    const int tx0    = (blockIdx.x & 3) << 4;
    const int l31    = lane & 31;
    const int loct   = lane >> 5;

    __shared__ __align__(16) _Float16 sH[832 * 8];   // 2 planes x 416 granules
    __shared__ __align__(16) _Float16 sL[832 * 8];

    f32x16 acc[2][2];
#pragma unroll
    for (int i = 0; i < 2; ++i)
#pragma unroll
        for (int j = 0; j < 2; ++j)
#pragma unroll
            for (int r = 0; r < 16; ++r) acc[i][j][r] = 0.f;

    const int wlb = ((cobase + l31) << 4) + (loct << 3);
    // per-mt pixel base (dy=dx=0): hp0 = row*20 + col
    int hp0[2];
#pragma unroll
    for (int mt = 0; mt < 2; ++mt) {
        const int px = ((wave << 1) + mt) << 5 | l31;
        hp0[mt] = (px >> 4) * 20 + (px & 15);
    }

#pragma unroll 1
    for (int cc = 0; cc < 4; ++cc) {
        __syncthreads();                         // prev compute done with LDS
        // ---- async stage: 26 x global_load_lds(16B), wave-strided ----
        for (int i = wave; i < 26; i += 4) {
            const int ii = (i < 13) ? i : (i - 13);
            _Float16* sbuf = (i < 13) ? sH : sL;
            const _Float16* gb = (i < 13) ? pnh : pnl;
            const int d  = (ii << 6) + lane;
            const int c  = (d >= 416) ? 1 : 0;
            const int px = d - (c << 4) * 26;    // d - 416*c
            const int r  = px / 20;
            const int col = px - 20 * r;
            const int gy = ty0 - 2 + r;
            const int gx = tx0 - 2 + col;
            const void* src = zp;
            if (px < 400 && (unsigned)gy < 64u && (unsigned)gx < 64u) {
                src = gb + ((((size_t)b << 12) + (gy << 6) + gx) << 6)
                         + (cc << 4) + (c << 3);
            }
            gload_lds16(src, (char*)sbuf + (ii << 10));
        }
        __syncthreads();                         // drains vmcnt -> LDS valid

        // ---- 25 taps, single weight buffer, tight non-unrolled loop ----
        const _Float16* wph = whi + (size_t)cc * 25 * 2048 + wlb;
        const _Float16* wpl = wlo + (size_t)cc * 25 * 2048 + wlb;
        int hpoff = 0, dxc = 0;
#pragma unroll 1
        for (int t = 0; t < 25; ++t) {
            WFrag2 w;
            w.h[0] = *(const half8*)(wph);
            w.h[1] = *(const half8*)(wph + 512);
            w.l[0] = *(const half8*)(wpl);
            w.l[1] = *(const half8*)(wpl + 512);

            half8 aH[2], aL[2];
#pragma unroll
            for (int mt = 0; mt < 2; ++mt) {
                const int g = loct * 416 + hp0[mt] + hpoff;
                aH[mt] = *(const half8*)((const char*)sH + (g << 4));
                aL[mt] = *(const half8*)((const char*)sL + (g << 4));
            }

            __builtin_amdgcn_s_setprio(1);
            // pass-major: 4 independent MFMAs per pass (per-acc order fixed)
#pragma unroll
            for (int mt = 0; mt < 2; ++mt)
#pragma unroll
                for (int nt = 0; nt < 2; ++nt)
                    acc[mt][nt] = __builtin_amdgcn_mfma_f32_32x32x16_f16(
                        aH[mt], w.h[nt], acc[mt][nt], 0, 0, 0);
#pragma unroll
            for (int mt = 0; mt < 2; ++mt)
#pragma unroll
                for (int nt = 0; nt < 2; ++nt)
                    acc[mt][nt] = __builtin_amdgcn_mfma_f32_32x32x16_f16(
                        aH[mt], w.l[nt], acc[mt][nt], 0, 0, 0);
#pragma unroll
            for (int mt = 0; mt < 2; ++mt)
#pragma unroll
                for (int nt = 0; nt < 2; ++nt)
                    acc[mt][nt] = __builtin_amdgcn_mfma_f32_32x32x16_f16(
                        aL[mt], w.h[nt], acc[mt][nt], 0, 0, 0);
            __builtin_amdgcn_s_setprio(0);

            wph += 2048;
            wpl += 2048;
            hpoff += 1;
            if (++dxc == 5) { dxc = 0; hpoff += 15; }   // next tap row
        }
    }

    // ---- epilogue: U, S, flag, fused 2x2 pool ----
#pragma unroll
    for (int nt = 0; nt < 2; ++nt) {
        const int co = cobase + (nt << 5) + l31;
        const float bv = bias[co];
        const int plane = b * COUT + co;
#pragma unroll
        for (int mt = 0; mt < 2; ++mt) {
            const int m = (wave << 1) + mt;
            float us[4][4];
#pragma unroll
            for (int rg = 0; rg < 4; ++rg) {
                const int y  = ty0 + (m << 1) + (rg >> 1);
                const int xb = ((rg & 1) << 3) + (loct << 2);
                const size_t ro = ((size_t)plane << 12) + (y << 6) + tx0 + xb;
                float4 r4 = *(const float4*)&R[ro];
                us[rg][0] = acc[mt][nt][(rg << 2) + 0] + bv - gamma * r4.x;
                us[rg][1] = acc[mt][nt][(rg << 2) + 1] + bv - gamma * r4.y;
                us[rg][2] = acc[mt][nt][(rg << 2) + 2] + bv - gamma * r4.z;
                us[rg][3] = acc[mt][nt][(rg << 2) + 3] + bv - gamma * r4.w;
                float4 uq = make_float4(us[rg][0], us[rg][1], us[rg][2], us[rg][3]);
                float4 sq = make_float4(us[rg][0] > 1.f ? 1.f : 0.f,
                                        us[rg][1] > 1.f ? 1.f : 0.f,
                                        us[rg][2] > 1.f ? 1.f : 0.f,
                                        us[rg][3] > 1.f ? 1.f : 0.f);
                *(float4*)&out[ro] = sq;
                *(float4*)&out[(size_t)NPIX + ro] = uq;
#pragma unroll
                for (int j = 0; j < 4; ++j) {
                    if (fabsf(us[rg][j] - 1.f) < TAU) {
                        unsigned pos = atomicAdd(cnt, 1u);
                        if (pos < (unsigned)cap)
                            list[pos] = (int)(ro + j);
                    }
                }
            }
            const int py  = (ty0 >> 1) + m;
            const int pxb = (tx0 >> 1) + (loct << 1);
            float* pp = pooled + ((size_t)plane << 10) + (py << 5);
            float2 pA, pB;
            pA.x = (fmaxf(fmaxf(us[0][0], us[0][1]), fmaxf(us[2][0], us[2][1])) > 1.f) ? 1.f : 0.f;
            pA.y = (fmaxf(fmaxf(us[0][2], us[0][3]), fmaxf(us[2][2], us[2][3])) > 1.f) ? 1.f : 0.f;
            pB.x = (fmaxf(fmaxf(us[1][0], us[1][1]), fmaxf(us[3][0], us[3][1])) > 1.f) ? 1.f : 0.f;
            pB.y = (fmaxf(fmaxf(us[1][2], us[1][3]), fmaxf(us[3][2], us[3][3])) > 1.f) ? 1.f : 0.f;
            *(float2*)(pp + pxb) = pA;
            *(float2*)(pp + pxb + 4) = pB;
        }
    }
}

// ---------------------------------------------------------------------------
// Fallback conv (register staging) — used only if ws too small for pn path.
// ---------------------------------------------------------------------------
__global__ __launch_bounds__(256) void lif_conv_mfma_reg_kernel(
    const float* __restrict__ P, const float* __restrict__ Q,
    const float* __restrict__ R, const _Float16* __restrict__ whi,
    const _Float16* __restrict__ wlo, const float* __restrict__ bias,
    float* __restrict__ out, float* __restrict__ pooled,
    unsigned* __restrict__ cnt, int* __restrict__ list, int cap, int do_pool,
    float alpha, float oma, float gamma)
{
    const int tid  = threadIdx.x;
    const int wave = tid >> 6;
    const int lane = tid & 63;
    const int b      = blockIdx.z;
    const int cobase = blockIdx.y << 6;
    const int ty0    = (blockIdx.x >> 2) << 4;
    const int tx0    = (blockIdx.x & 3) << 4;
    const int l31    = lane & 31;
    const int loct   = lane >> 5;

    __shared__ __align__(16) _Float16 sH[6400];
    __shared__ __align__(16) _Float16 sL[6400];

    f32x16 acc[2][2];
#pragma unroll
    for (int i = 0; i < 2; ++i)
#pragma unroll
        for (int j = 0; j < 2; ++j)
#pragma unroll
            for (int r = 0; r < 16; ++r) acc[i][j][r] = 0.f;

    const int wlb = ((cobase + l31) << 4) + (loct << 3);

    for (int cc = 0; cc < 4; ++cc) {
        __syncthreads();
        for (int e = tid; e < 1024; e += 256) {
            int px = e & 511;
            int hh = e >> 9;
            if (px >= 400) continue;
            int r  = px / 20;
            int c_ = px - 20 * r;
            int gy = ty0 - 2 + r;
            int gx = tx0 - 2 + c_;
            half8 hv, lv;
            if ((unsigned)gy < 64u && (unsigned)gx < 64u) {
                const size_t pb = ((size_t)(b * CIN + (cc << 4) + (hh << 3)) << 12)
                                + (gy << 6) + gx;
                const float* Pp = P + pb;
                const float* Qp = Q + pb;
#pragma unroll
                for (int j = 0; j < 8; ++j) {
                    float pn = alpha * Pp[j << 12] + oma * Qp[j << 12];
                    _Float16 h = (_Float16)pn;
                    hv[j] = h;
                    lv[j] = (_Float16)(pn - (float)h);
                }
            } else {
#pragma unroll
                for (int j = 0; j < 8; ++j) { hv[j] = (_Float16)0.f; lv[j] = (_Float16)0.f; }
            }
            int a = (px << 5) + (hh << 4);
            a ^= ((px >> 2) & 1) << 4;
            *(half8*)((char*)sH + a) = hv;
            *(half8*)((char*)sL + a) = lv;
        }
        __syncthreads();

        const _Float16* wh  = whi + (size_t)cc * 25 * 2048 + wlb;
        const _Float16* wl_ = wlo + (size_t)cc * 25 * 2048 + wlb;
#pragma unroll 1
        for (int t = 0; t < 25; ++t) {
            WFrag2 w;
#pragma unroll
            for (int nt = 0; nt < 2; ++nt) {
                w.h[nt] = *(const half8*)(wh + (size_t)t * 2048 + (nt << 9));
                w.l[nt] = *(const half8*)(wl_ + (size_t)t * 2048 + (nt << 9));
            }
            const int dy = t / 5;
            const int dx = t - 5 * dy;
            half8 aH[2], aL[2];
#pragma unroll
            for (int mt = 0; mt < 2; ++mt) {
                const int px = ((wave << 1) + mt) << 5 | l31;
                const int hp = ((px >> 4) + dy) * 20 + (px & 15) + dx;
                int a = (hp << 5) + (loct << 4);
                a ^= ((hp >> 2) & 1) << 4;
                aH[mt] = *(const half8*)((const char*)sH + a);
                aL[mt] = *(const half8*)((const char*)sL + a);
            }
            __builtin_amdgcn_s_setprio(1);
#pragma unroll
            for (int mt = 0; mt < 2; ++mt)
#pragma unroll
                for (int nt = 0; nt < 2; ++nt)
                    acc[mt][nt] = __builtin_amdgcn_mfma_f32_32x32x16_f16(
                        aH[mt], w.h[nt], acc[mt][nt], 0, 0, 0);
#pragma unroll
            for (int mt = 0; mt < 2; ++mt)
#pragma unroll
                for (int nt = 0; nt < 2; ++nt)
                    acc[mt][nt] = __builtin_amdgcn_mfma_f32_32x32x16_f16(
                        aH[mt], w.l[nt], acc[mt][nt], 0, 0, 0);
#pragma unroll
            for (int mt = 0; mt < 2; ++mt)
#pragma unroll
                for (int nt = 0; nt < 2; ++nt)
                    acc[mt][nt] = __builtin_amdgcn_mfma_f32_32x32x16_f16(
                        aL[mt], w.h[nt], acc[mt][nt], 0, 0, 0);
            __builtin_amdgcn_s_setprio(0);
        }
    }

#pragma unroll
    for (int nt = 0; nt < 2; ++nt) {
        const int co = cobase + (nt << 5) + l31;
        const float bv = bias[co];
        const int plane = b * COUT + co;
#pragma unroll
        for (int mt = 0; mt < 2; ++mt) {
            const int m = (wave << 1) + mt;
            float us[4][4];
#pragma unroll
            for (int rg = 0; rg < 4; ++rg) {
                const int y  = ty0 + (m << 1) + (rg >> 1);
                const int xb = ((rg & 1) << 3) + (loct << 2);
                const size_t ro = ((size_t)plane << 12) + (y << 6) + tx0 + xb;
                float4 r4 = *(const float4*)&R[ro];
                us[rg][0] = acc[mt][nt][(rg << 2) + 0] + bv - gamma * r4.x;
                us[rg][1] = acc[mt][nt][(rg << 2) + 1] + bv - gamma * r4.y;
                us[rg][2] = acc[mt][nt][(rg << 2) + 2] + bv - gamma * r4.z;
                us[rg][3] = acc[mt][nt][(rg << 2) + 3] + bv - gamma * r4.w;
                float4 uq = make_float4(us[rg][0], us[rg][1], us[rg][2], us[rg][3]);
                float4 sq = make_float4(us[rg][0] > 1.f ? 1.f : 0.f,
                                        us[rg][1] > 1.f ? 1.f : 0.f,
                                        us[rg][2] > 1.f ? 1.f : 0.f,
                                        us[rg][3] > 1.f ? 1.f : 0.f);
                *(float4*)&out[ro] = sq;
                *(float4*)&out[(size_t)NPIX + ro] = uq;
#pragma unroll
                for (int j = 0; j < 4; ++j) {
                    if (fabsf(us[rg][j] - 1.f) < TAU) {
                        unsigned pos = atomicAdd(cnt, 1u);
                        if (pos < (unsigned)cap)
                            list[pos] = (int)(ro + j);
                    }
                }
            }
            if (do_pool) {
                const int py  = (ty0 >> 1) + m;
                const int pxb = (tx0 >> 1) + (loct << 1);
                float* pp = pooled + ((size_t)plane << 10) + (py << 5);
                float2 pA, pB;
                pA.x = (fmaxf(fmaxf(us[0][0], us[0][1]), fmaxf(us[2][0], us[2][1])) > 1.f) ? 1.f : 0.f;
                pA.y = (fmaxf(fmaxf(us[0][2], us[0][3]), fmaxf(us[2][2], us[2][3])) > 1.f) ? 1.f : 0.f;
                pB.x = (fmaxf(fmaxf(us[1][0], us[1][1]), fmaxf(us[3][0], us[3][1])) > 1.f) ? 1.f : 0.f;
                pB.y = (fmaxf(fmaxf(us[1][2], us[1][3]), fmaxf(us[3][2], us[3][3])) > 1.f) ? 1.f : 0.f;
                *(float2*)(pp + pxb) = pA;
                *(float2*)(pp + pxb + 4) = pB;
            }
        }
    }
}

// ---------------------------------------------------------------------------
// Wave-parallel f64 repair: one wave per flagged element, lane = cin.
// ---------------------------------------------------------------------------
__global__ __launch_bounds__(256) void repair_list_kernel(
    const float* __restrict__ P, const float* __restrict__ Q,
    const float* __restrict__ R, const float* __restrict__ W,
    const float* __restrict__ bias, float* __restrict__ out,
    const unsigned* __restrict__ cnt, const int* __restrict__ list, int cap,
    double alpha, double oma, double gamma)
{
    const int nrep = (int)min(*cnt, (unsigned)cap);
    const int wid  = (blockIdx.x * 256 + threadIdx.x) >> 6;
    const int lane = threadIdx.x & 63;
    const int nw   = (gridDim.x * 256) >> 6;

    for (int i = wid; i < nrep; i += nw) {
        const int idx   = list[i];
        const int plane = idx >> 12;
        const int pix   = idx & 4095;
        const int oy    = pix >> 6;
        const int ox    = pix & 63;
        const int b     = plane >> 7;
        const int co    = plane & 127;

        const float* Pp = P + ((size_t)b * CIN + lane) * HWHW;
        const float* Qp = Q + ((size_t)b * CIN + lane) * HWHW;
        const float* Wp = W + ((size_t)co * CIN + lane) * 25;

        double acc = 0.0;
#pragma unroll
        for (int dy = 0; dy < 5; ++dy) {
            int iy = oy + dy - 2;
            if ((unsigned)iy >= 64u) continue;
#pragma unroll
            for (int dx = 0; dx < 5; ++dx) {
                int ix = ox + dx - 2;
                if ((unsigned)ix >= 64u) continue;
                int off = (iy << 6) + ix;
                double pn = alpha * (double)Pp[off] + oma * (double)Qp[off];
                acc = fma((double)Wp[dy * 5 + dx], pn, acc);
            }
        }
#pragma unroll
        for (int s = 32; s; s >>= 1) acc += __shfl_down(acc, s, 64);

        if (lane == 0) {
            double u64 = acc + (double)bias[co]
                       - gamma * (double)R[(size_t)plane * HWHW + pix];
            out[idx]                = (u64 > 1.0) ? 1.f : 0.f;
            out[(size_t)NPIX + idx] = (float)u64;
        }
    }
}

__global__ __launch_bounds__(256) void pool_fix_kernel(
    const float* __restrict__ out, float* __restrict__ pooled,
    const unsigned* __restrict__ cnt, const int* __restrict__ list, int cap)
{
    const int nrep = (int)min(*cnt, (unsigned)cap);
    for (int i = blockIdx.x * 256 + threadIdx.x; i < nrep; i += gridDim.x * 256) {
        int idx   = list[i];
        int plane = idx >> 12;
        int pix   = idx & 4095;
        int oy    = pix >> 6;
        int ox    = pix & 63;
        size_t base = ((size_t)plane << 12) + ((oy & ~1) << 6) + (ox & ~1);
        float m = fmaxf(fmaxf(out[base], out[base + 1]),
                        fmaxf(out[base + 64], out[base + 65]));
        pooled[((size_t)plane << 10) + ((oy >> 1) << 5) + (ox >> 1)] = m;
    }
}

__global__ void ro_init(float* ro)
{
    int i = blockIdx.x * 256 + threadIdx.x;
    if (i < 640) ro[i] = 0.5f;
}

__global__ __launch_bounds__(256) void readout_pooled_kernel(
    const float* __restrict__ pooled, const float* __restrict__ wsig,
    float* __restrict__ part)
{
    const int tid = threadIdx.x;
    const int c   = blockIdx.x;
    const int bg  = blockIdx.y;

    __shared__ float wl[10 * 1024];
    for (int i = tid; i < 10240; i += 256)
        wl[i] = wsig[(size_t)(i >> 10) * 131072 + (c << 10) + (i & 1023)];
    __syncthreads();

    __shared__ float psum[4][10];
    const int wave = tid >> 6;
    const int lane = tid & 63;

    for (int bi = 0; bi < 8; ++bi) {
        const int b = (bg << 3) + bi;
        const float* pp = pooled + (((size_t)b * COUT + c) << 10);
        float acc[10];
#pragma unroll
        for (int o = 0; o < 10; ++o) acc[o] = 0.f;
#pragma unroll
        for (int it = 0; it < 4; ++it) {
            int f = tid + (it << 8);
            float m = pp[f];
#pragma unroll
            for (int o = 0; o < 10; ++o)
                acc[o] = fmaf(m, wl[(o << 10) + f], acc[o]);
        }
#pragma unroll
        for (int o = 0; o < 10; ++o) {
            float v = acc[o];
            v += __shfl_down(v, 32, 64);
            v += __shfl_down(v, 16, 64);
            v += __shfl_down(v, 8, 64);
            v += __shfl_down(v, 4, 64);
            v += __shfl_down(v, 2, 64);
            v += __shfl_down(v, 1, 64);
            if (lane == 0) psum[wave][o] = v;
        }
        __syncthreads();
        if (tid < 10) {
            float s = psum[0][tid] + psum[1][tid] + psum[2][tid] + psum[3][tid];
            part[((size_t)b * 10 + tid) * 128 + c] = s;
        }
        __syncthreads();
    }
}

__global__ __launch_bounds__(256) void readout_reduce_kernel(
    const float* __restrict__ part, float* __restrict__ ro)
{
    int i = blockIdx.x * 256 + threadIdx.x;
    if (i >= 640) return;
    const float* pp = part + (size_t)i * 128;
    float s = 0.f;
#pragma unroll
    for (int c = 0; c < 128; ++c) s += pp[c];
    ro[i] = 0.5f * s + 0.5f;
}

__global__ __launch_bounds__(256) void readout_kernel(
    const float* __restrict__ S, const float* __restrict__ wsig,
    float* __restrict__ ro)
{
    const int tid = threadIdx.x;
    const int b = blockIdx.x >> 7;
    const int c = blockIdx.x & 127;

    __shared__ float wl[10 * 1024];
    for (int idx = tid; idx < 10240; idx += 256) {
        int o = idx >> 10;
        int f = idx & 1023;
        wl[idx] = wsig[(size_t)o * 131072 + (c << 10) + f];
    }
    __syncthreads();

    float acc[10];
#pragma unroll
    for (int o = 0; o < 10; ++o) acc[o] = 0.f;

    const float* Sp = S + ((size_t)b * COUT + c) * HWHW;
#pragma unroll
    for (int i = 0; i < 4; ++i) {
        int fl = tid + (i << 8);
        int ph = fl >> 5, pw = fl & 31;
        const float2 t0 = *(const float2*)&Sp[(ph << 7) + (pw << 1)];
        const float2 t1 = *(const float2*)&Sp[(ph << 7) + 64 + (pw << 1)];
        float m = fmaxf(fmaxf(t0.x, t0.y), fmaxf(t1.x, t1.y));
#pragma unroll
        for (int o = 0; o < 10; ++o)
            acc[o] = fmaf(m, wl[(o << 10) + fl], acc[o]);
    }

    __shared__ float psum[4][10];
    const int wave = tid >> 6;
    const int lane = tid & 63;
#pragma unroll
    for (int o = 0; o < 10; ++o) {
        float v = acc[o];
        v += __shfl_down(v, 32, 64);
        v += __shfl_down(v, 16, 64);
        v += __shfl_down(v, 8, 64);
        v += __shfl_down(v, 4, 64);
        v += __shfl_down(v, 2, 64);
        v += __shfl_down(v, 1, 64);
        if (lane == 0) psum[wave][o] = v;
    }
    __syncthreads();
    if (tid < 10) {
        float s = psum[0][tid] + psum[1][tid] + psum[2][tid] + psum[3][tid];
        atomicAdd(&ro[b * 10 + tid], 0.5f * s);
    }
}

extern "C" void kernel_launch(void* const* d_in, const int* in_sizes, int n_in,
                              void* d_out, int out_size, void* d_ws, size_t ws_size,
                              hipStream_t stream)
{
    const float* P    = (const float*)d_in[1];
    const float* Q    = (const float*)d_in[2];
    const float* R    = (const float*)d_in[3];
    const float* W    = (const float*)d_in[4];
    const float* bias = (const float*)d_in[5];
    const float* wsig = (const float*)d_in[6];
    float* out = (float*)d_out;

    const size_t wbytes      = (size_t)NW3 * 2 * 2;
    const size_t pooled_bytes = (size_t)POOLED_FLOATS * 4;
    const size_t part_bytes   = (size_t)PART_FLOATS * 4;
    const size_t pn_bytes     = (size_t)B_ * CIN * HWHW * 2;   // 33.55MB each

    const double alpha_d = exp(-1e-3 / 20e-3);
    const double oma_d   = 1.0 - alpha_d;
    const double gamma_d = exp(-1e-3 / 2.86e-3);

    // pn layout: cnt(0)|zp(256)| pooled | part | list(4MB) | pnh | pnl | w
    size_t off = 4096;
    size_t pooled_off = off; off += pooled_bytes;
    size_t part_off   = off; off += part_bytes;
    size_t list_off   = off; off += ((size_t)4 << 20);
    size_t pnh_off    = off; off += pn_bytes;
    size_t pnl_off    = off; off += pn_bytes;
    size_t w_off      = off; off += wbytes + 256;
    const int use_pn = (ws_size >= off);

    if (use_pn) {
        unsigned* cnt = (unsigned*)d_ws;
        const void* zp = (const void*)((char*)d_ws + 256);
        float* pooled = (float*)((char*)d_ws + pooled_off);
        float* part   = (float*)((char*)d_ws + part_off);
        int*   list   = (int*)((char*)d_ws + list_off);
        int    cap    = (1 << 20);
        _Float16* pnh = (_Float16*)((char*)d_ws + pnh_off);
        _Float16* pnl = (_Float16*)((char*)d_ws + pnl_off);
        _Float16* whi = (_Float16*)((char*)d_ws + w_off);
        _Float16* wlo = whi + NW3;

        (void)hipMemsetAsync(d_ws, 0, 512, stream);   // cnt + zero-page

        wprep_kernel<<<(NW3 + 255) / 256, 256, 0, stream>>>(W, whi, wlo);
        pnprep_kernel<<<dim3(64, 64), 256, 0, stream>>>(P, Q, pnh, pnl,
                                                        (float)alpha_d, (float)oma_d);

        dim3 grid(16, 2, 64);
        lif_conv_mfma_pn_kernel<<<grid, 256, 0, stream>>>(pnh, pnl, R, whi, wlo,
                                                          bias, out, pooled, zp,
                                                          cnt, list, cap,
                                                          (float)gamma_d);

        repair_list_kernel<<<2048, 256, 0, stream>>>(P, Q, R, W, bias, out,
                                                     cnt, list, cap,
                                                     alpha_d, oma_d, gamma_d);
        pool_fix_kernel<<<64, 256, 0, stream>>>(out, pooled, cnt, list, cap);
        readout_pooled_kernel<<<dim3(128, 8), 256, 0, stream>>>(pooled, wsig, part);
        readout_reduce_kernel<<<3, 256, 0, stream>>>(part, out + (size_t)2 * NPIX);
        return;
    }

    // -------- fallback path --------
    size_t wsoff = (ws_size - wbytes) & ~(size_t)63;
    _Float16* whi = (_Float16*)((char*)d_ws + wsoff);
    _Float16* wlo = whi + NW3;
    unsigned* cnt = (unsigned*)d_ws;

    const int use_pooled = ws_size >= 64 + pooled_bytes + part_bytes
                                     + (1u << 22) + wbytes + 64;
    float* pooled = use_pooled ? (float*)((char*)d_ws + 64) : (float*)d_ws;
    float* part   = use_pooled ? (float*)((char*)d_ws + 64 + pooled_bytes)
                               : (float*)d_ws;
    size_t listoff = use_pooled ? (64 + pooled_bytes + part_bytes) : 16;
    int* list = (int*)((char*)d_ws + listoff);
    size_t cap_sz = (wsoff > listoff) ? (wsoff - listoff) / 4 : 0;
    int cap = (int)(cap_sz > (size_t)NPIX ? (size_t)NPIX : cap_sz);

    (void)hipMemsetAsync(d_ws, 0, 16, stream);

    wprep_kernel<<<(NW3 + 255) / 256, 256, 0, stream>>>(W, whi, wlo);

    dim3 grid(16, 2, 64);
    lif_conv_mfma_reg_kernel<<<grid, 256, 0, stream>>>(P, Q, R, whi, wlo, bias,
                                                       out, pooled, cnt, list, cap,
                                                       use_pooled,
                                                       (float)alpha_d, (float)oma_d,
                                                       (float)gamma_d);

    repair_list_kernel<<<2048, 256, 0, stream>>>(P, Q, R, W, bias, out,
                                                 cnt, list, cap,
                                                 alpha_d, oma_d, gamma_d);

    if (use_pooled) {
        pool_fix_kernel<<<64, 256, 0, stream>>>(out, pooled, cnt, list, cap);
        readout_pooled_kernel<<<dim3(128, 8), 256, 0, stream>>>(pooled, wsig, part);
        readout_reduce_kernel<<<3, 256, 0, stream>>>(part, out + (size_t)2 * NPIX);
    } else {
        float* ro = out + (size_t)2 * NPIX;
        ro_init<<<3, 256, 0, stream>>>(ro);
        readout_kernel<<<8192, 256, 0, stream>>>(out, wsig, ro);
    }
}

// Round 17
// 489.956 us; speedup vs baseline: 1.3203x; 1.3203x over previous
//
#include <hip/hip_runtime.h>
#include <math.h>

#define B_    64
#define CIN   64
#define COUT  128
#define HWHW  4096   // 64*64
#define NPIX  (B_ * COUT * HWHW)   // 33,554,432 per output map
#define TAU   1e-4f
#define NW3   204800               // 4 cc * 25 tap * 128 cout * 16 k
#define POOLED_FLOATS (B_ * COUT * 1024)   // 8,388,608
#define PART_FLOATS   (B_ * 10 * COUT)     // 81,920
#define PNS   66                   // pnprep LDS stride (bank-safe transpose)

typedef _Float16 half8  __attribute__((ext_vector_type(8)));
typedef _Float16 half2v __attribute__((ext_vector_type(2)));
typedef float    f32x4  __attribute__((ext_vector_type(4)));
typedef float    f32x16 __attribute__((ext_vector_type(16)));

__device__ __forceinline__ void gload_lds16(const void* g, void* l)
{
    __builtin_amdgcn_global_load_lds(
        (const __attribute__((address_space(1))) unsigned int*)g,
        (__attribute__((address_space(3))) unsigned int*)l, 16, 0, 0);
}

// ---------------------------------------------------------------------------
// Weight pre-transform: W[cout][cin][5][5] f32 ->
//   whi/wlo [cc(4)][tap(25)][cout(128)][k(16)] f16, cin = cc*16 + k.
// ---------------------------------------------------------------------------
__global__ __launch_bounds__(256) void wprep_kernel(
    const float* __restrict__ W, _Float16* __restrict__ whi,
    _Float16* __restrict__ wlo)
{
    int e = blockIdx.x * 256 + threadIdx.x;
    if (e >= NW3) return;
    int k   = e & 15;
    int co  = (e >> 4) & 127;
    int r   = e >> 11;
    int tap = r % 25;
    int cc  = r / 25;
    float w = W[(size_t)((co << 6) + (cc << 4) + k) * 25 + tap];
    _Float16 h = (_Float16)w;
    whi[e] = h;
    wlo[e] = (_Float16)(w - (float)h);
}

// ---------------------------------------------------------------------------
// P_new pre-pass: pn = a*P + (1-a)*Q (f32), split f16 hi/lo, channels-last:
//   pn[((b*64+y)*64+x)*64 + cin]
// ---------------------------------------------------------------------------
__global__ __launch_bounds__(256) void pnprep_kernel(
    const float* __restrict__ P, const float* __restrict__ Q,
    _Float16* __restrict__ pnh, _Float16* __restrict__ pnl,
    float alpha, float oma)
{
    const int tid = threadIdx.x;
    const int y   = blockIdx.x;
    const int b   = blockIdx.y;
    __shared__ _Float16 th[64 * PNS];
    __shared__ _Float16 tl[64 * PNS];

    const size_t rb = (size_t)b * CIN * HWHW + ((size_t)y << 6);
#pragma unroll
    for (int k = 0; k < 4; ++k) {
        int idx = tid + (k << 8);            // 0..1023
        int cin = idx >> 4;
        int x0  = (idx & 15) << 2;
        float4 p4 = *(const float4*)(P + rb + (size_t)cin * HWHW + x0);
        float4 q4 = *(const float4*)(Q + rb + (size_t)cin * HWHW + x0);
        float pn[4] = { alpha * p4.x + oma * q4.x, alpha * p4.y + oma * q4.y,
                        alpha * p4.z + oma * q4.z, alpha * p4.w + oma * q4.w };
        half2v h0, h1, l0, l1;
        {
            _Float16 a0 = (_Float16)pn[0], a1 = (_Float16)pn[1];
            _Float16 a2 = (_Float16)pn[2], a3 = (_Float16)pn[3];
            h0[0] = a0; h0[1] = a1; h1[0] = a2; h1[1] = a3;
            l0[0] = (_Float16)(pn[0] - (float)a0);
            l0[1] = (_Float16)(pn[1] - (float)a1);
            l1[0] = (_Float16)(pn[2] - (float)a2);
            l1[1] = (_Float16)(pn[3] - (float)a3);
        }
        int base = cin * PNS + x0;           // 4B-aligned (x0 even)
        *(half2v*)&th[base]     = h0;
        *(half2v*)&th[base + 2] = h1;
        *(half2v*)&tl[base]     = l0;
        *(half2v*)&tl[base + 2] = l1;
    }
    __syncthreads();

    const size_t ob = ((((size_t)b << 12) + ((size_t)y << 6)) << 6);  // f16 units
#pragma unroll
    for (int k = 0; k < 2; ++k) {
        int gg  = tid + (k << 8);            // 0..511
        int x   = gg >> 3;
        int oct = gg & 7;
        half8 hv, lv;
#pragma unroll
        for (int j = 0; j < 8; ++j) {
            hv[j] = th[(oct * 8 + j) * PNS + x];
            lv[j] = tl[(oct * 8 + j) * PNS + x];
        }
        *(half8*)(pnh + ob + ((size_t)x << 6) + (oct << 3)) = hv;
        *(half8*)(pnl + ob + ((size_t)x << 6) + (oct << 3)) = lv;
    }
}

// ---------------------------------------------------------------------------
// MFMA conv, round-17: exact round-13 tap/stage code (best conv: 370us)
// + LDS DOUBLE-BUFFER across cc chunks: stage cc+1 into other buffer, run
// cc's 25 taps, ONE sync per cc (was: dedicated stage-drain barrier 4x).
// Weight vmcnt waits partially drain staging during early taps (count-based
// counter) — worst case equals the old barrier stall, best case hides it.
// ---------------------------------------------------------------------------
struct WFrag2 { half8 h[2]; half8 l[2]; };

__global__ __launch_bounds__(256) void lif_conv_mfma_pn_kernel(
    const _Float16* __restrict__ pnh, const _Float16* __restrict__ pnl,
    const float* __restrict__ R, const _Float16* __restrict__ whi,
    const _Float16* __restrict__ wlo, const float* __restrict__ bias,
    float* __restrict__ out, float* __restrict__ pooled,
    const void* __restrict__ zp,
    unsigned* __restrict__ cnt, int* __restrict__ list, int cap,
    float gamma)
{
    const int tid  = threadIdx.x;
    const int wave = tid >> 6;
    const int lane = tid & 63;
    const int b      = blockIdx.z;
    const int cobase = blockIdx.y << 6;          // 0 or 64
    const int ty0    = (blockIdx.x >> 2) << 4;
    const int tx0    = (blockIdx.x & 3) << 4;
    const int l31    = lane & 31;
    const int loct   = lane >> 5;

    __shared__ __align__(16) _Float16 sH[2][416 * 16];   // 2 x 13 KiB
    __shared__ __align__(16) _Float16 sL[2][416 * 16];

    f32x16 acc[2][2];
#pragma unroll
    for (int i = 0; i < 2; ++i)
#pragma unroll
        for (int j = 0; j < 2; ++j)
#pragma unroll
            for (int r = 0; r < 16; ++r) acc[i][j][r] = 0.f;

    const int wlb = ((cobase + l31) << 4) + (loct << 3);

    // ---- stage helper: 26 x async 16B gload_lds for chunk cc -> buf ----
    auto stage = [&](int cc, int bufi) {
        for (int i = wave; i < 26; i += 4) {
            const int ii = (i < 13) ? i : (i - 13);
            _Float16* sbuf = (i < 13) ? &sH[bufi][0] : &sL[bufi][0];
            const _Float16* gb = (i < 13) ? pnh : pnl;
            const int g  = (ii << 6) + lane;     // dest granule
            const int px = g >> 1;
            const int c  = g & 1;
            const int r  = px / 20;
            const int col = px - 20 * r;
            const int gy = ty0 - 2 + r;
            const int gx = tx0 - 2 + col;
            const void* src = zp;
            if (px < 400 && (unsigned)gy < 64u && (unsigned)gx < 64u) {
                const int cs = c ^ ((px >> 2) & 1);   // source-side swizzle
                src = gb + ((((size_t)b << 12) + (gy << 6) + gx) << 6)
                         + (cc << 4) + (cs << 3);
            }
            gload_lds16(src, (char*)sbuf + (ii << 10));
        }
    };

    stage(0, 0);
    __syncthreads();                             // buf0 ready

    for (int cc = 0; cc < 4; ++cc) {
        if (cc < 3) stage(cc + 1, (cc + 1) & 1); // async into other buffer

        const _Float16* sHc = &sH[cc & 1][0];
        const _Float16* sLc = &sL[cc & 1][0];

        // ---- 25 taps, weight ping-pong pipeline (round-13 exact) ----
        const _Float16* wh  = whi + (size_t)cc * 25 * 2048 + wlb;
        const _Float16* wl_ = wlo + (size_t)cc * 25 * 2048 + wlb;
        WFrag2 wbuf[2];
#pragma unroll
        for (int nt = 0; nt < 2; ++nt) {
            wbuf[0].h[nt] = *(const half8*)(wh + (nt << 9));
            wbuf[0].l[nt] = *(const half8*)(wl_ + (nt << 9));
        }
#pragma unroll
        for (int t = 0; t < 25; ++t) {
            {
                const int tn = (t < 24) ? (t + 1) : 24;
                WFrag2& wn = wbuf[(t + 1) & 1];
#pragma unroll
                for (int nt = 0; nt < 2; ++nt) {
                    wn.h[nt] = *(const half8*)(wh + (size_t)tn * 2048 + (nt << 9));
                    wn.l[nt] = *(const half8*)(wl_ + (size_t)tn * 2048 + (nt << 9));
                }
            }
            __builtin_amdgcn_sched_barrier(0);

            const WFrag2& w = wbuf[t & 1];
            const int dy = t / 5;
            const int dx = t - 5 * dy;

            half8 aH[2], aL[2];
#pragma unroll
            for (int mt = 0; mt < 2; ++mt) {
                const int px = ((wave << 1) + mt) << 5 | l31;
                const int hp = ((px >> 4) + dy) * 20 + (px & 15) + dx;
                int a = (hp << 5) + (loct << 4);
                a ^= ((hp >> 2) & 1) << 4;
                aH[mt] = *(const half8*)((const char*)sHc + a);
                aL[mt] = *(const half8*)((const char*)sLc + a);
            }

            __builtin_amdgcn_s_setprio(1);
#pragma unroll
            for (int mt = 0; mt < 2; ++mt) {
#pragma unroll
                for (int nt = 0; nt < 2; ++nt) {
                    acc[mt][nt] = __builtin_amdgcn_mfma_f32_32x32x16_f16(
                        aH[mt], w.h[nt], acc[mt][nt], 0, 0, 0);
                    acc[mt][nt] = __builtin_amdgcn_mfma_f32_32x32x16_f16(
                        aH[mt], w.l[nt], acc[mt][nt], 0, 0, 0);
                    acc[mt][nt] = __builtin_amdgcn_mfma_f32_32x32x16_f16(
                        aL[mt], w.h[nt], acc[mt][nt], 0, 0, 0);
                }
            }
            __builtin_amdgcn_s_setprio(0);
        }

        __syncthreads();   // drains this wave's staging loads; all waves done
    }

    // ---- epilogue: U, S, flag, fused 2x2 pool (round-11 mapping) ----
#pragma unroll
    for (int nt = 0; nt < 2; ++nt) {
        const int co = cobase + (nt << 5) + l31;
        const float bv = bias[co];
        const int plane = b * COUT + co;
#pragma unroll
        for (int mt = 0; mt < 2; ++mt) {
            const int m = (wave << 1) + mt;
            float us[4][4];
#pragma unroll
            for (int rg = 0; rg < 4; ++rg) {
                const int y  = ty0 + (m << 1) + (rg >> 1);
                const int xb = ((rg & 1) << 3) + (loct << 2);
                const size_t ro = ((size_t)plane << 12) + (y << 6) + tx0 + xb;
                float4 r4 = *(const float4*)&R[ro];
                us[rg][0] = acc[mt][nt][(rg << 2) + 0] + bv - gamma * r4.x;
                us[rg][1] = acc[mt][nt][(rg << 2) + 1] + bv - gamma * r4.y;
                us[rg][2] = acc[mt][nt][(rg << 2) + 2] + bv - gamma * r4.z;
                us[rg][3] = acc[mt][nt][(rg << 2) + 3] + bv - gamma * r4.w;
                float4 uq = make_float4(us[rg][0], us[rg][1], us[rg][2], us[rg][3]);
                float4 sq = make_float4(us[rg][0] > 1.f ? 1.f : 0.f,
                                        us[rg][1] > 1.f ? 1.f : 0.f,
                                        us[rg][2] > 1.f ? 1.f : 0.f,
                                        us[rg][3] > 1.f ? 1.f : 0.f);
                *(float4*)&out[ro] = sq;
                *(float4*)&out[(size_t)NPIX + ro] = uq;
#pragma unroll
                for (int j = 0; j < 4; ++j) {
                    if (fabsf(us[rg][j] - 1.f) < TAU) {
                        unsigned pos = atomicAdd(cnt, 1u);
                        if (pos < (unsigned)cap)
                            list[pos] = (int)(ro + j);
                    }
                }
            }
            const int py  = (ty0 >> 1) + m;
            const int pxb = (tx0 >> 1) + (loct << 1);
            float* pp = pooled + ((size_t)plane << 10) + (py << 5);
            float2 pA, pB;
            pA.x = (fmaxf(fmaxf(us[0][0], us[0][1]), fmaxf(us[2][0], us[2][1])) > 1.f) ? 1.f : 0.f;
            pA.y = (fmaxf(fmaxf(us[0][2], us[0][3]), fmaxf(us[2][2], us[2][3])) > 1.f) ? 1.f : 0.f;
            pB.x = (fmaxf(fmaxf(us[1][0], us[1][1]), fmaxf(us[3][0], us[3][1])) > 1.f) ? 1.f : 0.f;
            pB.y = (fmaxf(fmaxf(us[1][2], us[1][3]), fmaxf(us[3][2], us[3][3])) > 1.f) ? 1.f : 0.f;
            *(float2*)(pp + pxb) = pA;
            *(float2*)(pp + pxb + 4) = pB;
        }
    }
}

// ---------------------------------------------------------------------------
// Fallback conv (register staging) — used only if ws too small for pn path.
// ---------------------------------------------------------------------------
__global__ __launch_bounds__(256) void lif_conv_mfma_reg_kernel(
    const float* __restrict__ P, const float* __restrict__ Q,
    const float* __restrict__ R, const _Float16* __restrict__ whi,
    const _Float16* __restrict__ wlo, const float* __restrict__ bias,
    float* __restrict__ out, float* __restrict__ pooled,
    unsigned* __restrict__ cnt, int* __restrict__ list, int cap, int do_pool,
    float alpha, float oma, float gamma)
{
    const int tid  = threadIdx.x;
    const int wave = tid >> 6;
    const int lane = tid & 63;
    const int b      = blockIdx.z;
    const int cobase = blockIdx.y << 6;
    const int ty0    = (blockIdx.x >> 2) << 4;
    const int tx0    = (blockIdx.x & 3) << 4;
    const int l31    = lane & 31;
    const int loct   = lane >> 5;

    __shared__ __align__(16) _Float16 sH[6400];
    __shared__ __align__(16) _Float16 sL[6400];

    f32x16 acc[2][2];
#pragma unroll
    for (int i = 0; i < 2; ++i)
#pragma unroll
        for (int j = 0; j < 2; ++j)
#pragma unroll
            for (int r = 0; r < 16; ++r) acc[i][j][r] = 0.f;

    const int wlb = ((cobase + l31) << 4) + (loct << 3);

    for (int cc = 0; cc < 4; ++cc) {
        __syncthreads();
        for (int e = tid; e < 1024; e += 256) {
            int px = e & 511;
            int hh = e >> 9;
            if (px >= 400) continue;
            int r  = px / 20;
            int c_ = px - 20 * r;
            int gy = ty0 - 2 + r;
            int gx = tx0 - 2 + c_;
            half8 hv, lv;
            if ((unsigned)gy < 64u && (unsigned)gx < 64u) {
                const size_t pb = ((size_t)(b * CIN + (cc << 4) + (hh << 3)) << 12)
                                + (gy << 6) + gx;
                const float* Pp = P + pb;
                const float* Qp = Q + pb;
#pragma unroll
                for (int j = 0; j < 8; ++j) {
                    float pn = alpha * Pp[j << 12] + oma * Qp[j << 12];
                    _Float16 h = (_Float16)pn;
                    hv[j] = h;
                    lv[j] = (_Float16)(pn - (float)h);
                }
            } else {
#pragma unroll
                for (int j = 0; j < 8; ++j) { hv[j] = (_Float16)0.f; lv[j] = (_Float16)0.f; }
            }
            int a = (px << 5) + (hh << 4);
            a ^= ((px >> 2) & 1) << 4;
            *(half8*)((char*)sH + a) = hv;
            *(half8*)((char*)sL + a) = lv;
        }
        __syncthreads();

        const _Float16* wh  = whi + (size_t)cc * 25 * 2048 + wlb;
        const _Float16* wl_ = wlo + (size_t)cc * 25 * 2048 + wlb;
        WFrag2 wbuf[2];
#pragma unroll
        for (int nt = 0; nt < 2; ++nt) {
            wbuf[0].h[nt] = *(const half8*)(wh + (nt << 9));
            wbuf[0].l[nt] = *(const half8*)(wl_ + (nt << 9));
        }
#pragma unroll
        for (int t = 0; t < 25; ++t) {
            {
                const int tn = (t < 24) ? (t + 1) : 24;
                WFrag2& wn = wbuf[(t + 1) & 1];
#pragma unroll
                for (int nt = 0; nt < 2; ++nt) {
                    wn.h[nt] = *(const half8*)(wh + (size_t)tn * 2048 + (nt << 9));
                    wn.l[nt] = *(const half8*)(wl_ + (size_t)tn * 2048 + (nt << 9));
                }
            }
            __builtin_amdgcn_sched_barrier(0);

            const WFrag2& w = wbuf[t & 1];
            const int dy = t / 5;
            const int dx = t - 5 * dy;
            half8 aH[2], aL[2];
#pragma unroll
            for (int mt = 0; mt < 2; ++mt) {
                const int px = ((wave << 1) + mt) << 5 | l31;
                const int hp = ((px >> 4) + dy) * 20 + (px & 15) + dx;
                int a = (hp << 5) + (loct << 4);
                a ^= ((hp >> 2) & 1) << 4;
                aH[mt] = *(const half8*)((const char*)sH + a);
                aL[mt] = *(const half8*)((const char*)sL + a);
            }
            __builtin_amdgcn_s_setprio(1);
#pragma unroll
            for (int mt = 0; mt < 2; ++mt) {
#pragma unroll
                for (int nt = 0; nt < 2; ++nt) {
                    acc[mt][nt] = __builtin_amdgcn_mfma_f32_32x32x16_f16(
                        aH[mt], w.h[nt], acc[mt][nt], 0, 0, 0);
                    acc[mt][nt] = __builtin_amdgcn_mfma_f32_32x32x16_f16(
                        aH[mt], w.l[nt], acc[mt][nt], 0, 0, 0);
                    acc[mt][nt] = __builtin_amdgcn_mfma_f32_32x32x16_f16(
                        aL[mt], w.h[nt], acc[mt][nt], 0, 0, 0);
                }
            }
            __builtin_amdgcn_s_setprio(0);
        }
    }

#pragma unroll
    for (int nt = 0; nt < 2; ++nt) {
        const int co = cobase + (nt << 5) + l31;
        const float bv = bias[co];
        const int plane = b * COUT + co;
#pragma unroll
        for (int mt = 0; mt < 2; ++mt) {
            const int m = (wave << 1) + mt;
            float us[4][4];
#pragma unroll
            for (int rg = 0; rg < 4; ++rg) {
                const int y  = ty0 + (m << 1) + (rg >> 1);
                const int xb = ((rg & 1) << 3) + (loct << 2);
                const size_t ro = ((size_t)plane << 12) + (y << 6) + tx0 + xb;
                float4 r4 = *(const float4*)&R[ro];
                us[rg][0] = acc[mt][nt][(rg << 2) + 0] + bv - gamma * r4.x;
                us[rg][1] = acc[mt][nt][(rg << 2) + 1] + bv - gamma * r4.y;
                us[rg][2] = acc[mt][nt][(rg << 2) + 2] + bv - gamma * r4.z;
                us[rg][3] = acc[mt][nt][(rg << 2) + 3] + bv - gamma * r4.w;
                float4 uq = make_float4(us[rg][0], us[rg][1], us[rg][2], us[rg][3]);
                float4 sq = make_float4(us[rg][0] > 1.f ? 1.f : 0.f,
                                        us[rg][1] > 1.f ? 1.f : 0.f,
                                        us[rg][2] > 1.f ? 1.f : 0.f,
                                        us[rg][3] > 1.f ? 1.f : 0.f);
                *(float4*)&out[ro] = sq;
                *(float4*)&out[(size_t)NPIX + ro] = uq;
#pragma unroll
                for (int j = 0; j < 4; ++j) {
                    if (fabsf(us[rg][j] - 1.f) < TAU) {
                        unsigned pos = atomicAdd(cnt, 1u);
                        if (pos < (unsigned)cap)
                            list[pos] = (int)(ro + j);
                    }
                }
            }
            if (do_pool) {
                const int py  = (ty0 >> 1) + m;
                const int pxb = (tx0 >> 1) + (loct << 1);
                float* pp = pooled + ((size_t)plane << 10) + (py << 5);
                float2 pA, pB;
                pA.x = (fmaxf(fmaxf(us[0][0], us[0][1]), fmaxf(us[2][0], us[2][1])) > 1.f) ? 1.f : 0.f;
                pA.y = (fmaxf(fmaxf(us[0][2], us[0][3]), fmaxf(us[2][2], us[2][3])) > 1.f) ? 1.f : 0.f;
                pB.x = (fmaxf(fmaxf(us[1][0], us[1][1]), fmaxf(us[3][0], us[3][1])) > 1.f) ? 1.f : 0.f;
                pB.y = (fmaxf(fmaxf(us[1][2], us[1][3]), fmaxf(us[3][2], us[3][3])) > 1.f) ? 1.f : 0.f;
                *(float2*)(pp + pxb) = pA;
                *(float2*)(pp + pxb + 4) = pB;
            }
        }
    }
}

// ---------------------------------------------------------------------------
// Wave-parallel f64 repair: one wave per flagged element, lane = cin.
// Reads original f32 P,Q (exact inputs) — pn f16 split is NOT accurate
// enough for the repair path (lo-rounding ~1e-7 rel vs ~1e-7 nearest gap).
// ---------------------------------------------------------------------------
__global__ __launch_bounds__(256) void repair_list_kernel(
    const float* __restrict__ P, const float* __restrict__ Q,
    const float* __restrict__ R, const float* __restrict__ W,
    const float* __restrict__ bias, float* __restrict__ out,
    const unsigned* __restrict__ cnt, const int* __restrict__ list, int cap,
    double alpha, double oma, double gamma)
{
    const int nrep = (int)min(*cnt, (unsigned)cap);
    const int wid  = (blockIdx.x * 256 + threadIdx.x) >> 6;
    const int lane = threadIdx.x & 63;
    const int nw   = (gridDim.x * 256) >> 6;

    for (int i = wid; i < nrep; i += nw) {
        const int idx   = list[i];
        const int plane = idx >> 12;
        const int pix   = idx & 4095;
        const int oy    = pix >> 6;
        const int ox    = pix & 63;
        const int b     = plane >> 7;
        const int co    = plane & 127;

        const float* Pp = P + ((size_t)b * CIN + lane) * HWHW;
        const float* Qp = Q + ((size_t)b * CIN + lane) * HWHW;
        const float* Wp = W + ((size_t)co * CIN + lane) * 25;

        double acc = 0.0;
#pragma unroll
        for (int dy = 0; dy < 5; ++dy) {
            int iy = oy + dy - 2;
            if ((unsigned)iy >= 64u) continue;
#pragma unroll
            for (int dx = 0; dx < 5; ++dx) {
                int ix = ox + dx - 2;
                if ((unsigned)ix >= 64u) continue;
                int off = (iy << 6) + ix;
                double pn = alpha * (double)Pp[off] + oma * (double)Qp[off];
                acc = fma((double)Wp[dy * 5 + dx], pn, acc);
            }
        }
#pragma unroll
        for (int s = 32; s; s >>= 1) acc += __shfl_down(acc, s, 64);

        if (lane == 0) {
            double u64 = acc + (double)bias[co]
                       - gamma * (double)R[(size_t)plane * HWHW + pix];
            out[idx]                = (u64 > 1.0) ? 1.f : 0.f;
            out[(size_t)NPIX + idx] = (float)u64;
        }
    }
}

__global__ __launch_bounds__(256) void pool_fix_kernel(
    const float* __restrict__ out, float* __restrict__ pooled,
    const unsigned* __restrict__ cnt, const int* __restrict__ list, int cap)
{
    const int nrep = (int)min(*cnt, (unsigned)cap);
    for (int i = blockIdx.x * 256 + threadIdx.x; i < nrep; i += gridDim.x * 256) {
        int idx   = list[i];
        int plane = idx >> 12;
        int pix   = idx & 4095;
        int oy    = pix >> 6;
        int ox    = pix & 63;
        size_t base = ((size_t)plane << 12) + ((oy & ~1) << 6) + (ox & ~1);
        float m = fmaxf(fmaxf(out[base], out[base + 1]),
                        fmaxf(out[base + 64], out[base + 65]));
        pooled[((size_t)plane << 10) + ((oy >> 1) << 5) + (ox >> 1)] = m;
    }
}

__global__ void ro_init(float* ro)
{
    int i = blockIdx.x * 256 + threadIdx.x;
    if (i < 640) ro[i] = 0.5f;
}

__global__ __launch_bounds__(256) void readout_pooled_kernel(
    const float* __restrict__ pooled, const float* __restrict__ wsig,
    float* __restrict__ part)
{
    const int tid = threadIdx.x;
    const int c   = blockIdx.x;
    const int bg  = blockIdx.y;

    __shared__ float wl[10 * 1024];
    for (int i = tid; i < 10240; i += 256)
        wl[i] = wsig[(size_t)(i >> 10) * 131072 + (c << 10) + (i & 1023)];
    __syncthreads();

    __shared__ float psum[4][10];
    const int wave = tid >> 6;
    const int lane = tid & 63;

    for (int bi = 0; bi < 8; ++bi) {
        const int b = (bg << 3) + bi;
        const float* pp = pooled + (((size_t)b * COUT + c) << 10);
        float acc[10];
#pragma unroll
        for (int o = 0; o < 10; ++o) acc[o] = 0.f;
#pragma unroll
        for (int it = 0; it < 4; ++it) {
            int f = tid + (it << 8);
            float m = pp[f];
#pragma unroll
            for (int o = 0; o < 10; ++o)
                acc[o] = fmaf(m, wl[(o << 10) + f], acc[o]);
        }
#pragma unroll
        for (int o = 0; o < 10; ++o) {
            float v = acc[o];
            v += __shfl_down(v, 32, 64);
            v += __shfl_down(v, 16, 64);
            v += __shfl_down(v, 8, 64);
            v += __shfl_down(v, 4, 64);
            v += __shfl_down(v, 2, 64);
            v += __shfl_down(v, 1, 64);
            if (lane == 0) psum[wave][o] = v;
        }
        __syncthreads();
        if (tid < 10) {
            float s = psum[0][tid] + psum[1][tid] + psum[2][tid] + psum[3][tid];
            part[((size_t)b * 10 + tid) * 128 + c] = s;
        }
        __syncthreads();
    }
}

__global__ __launch_bounds__(256) void readout_reduce_kernel(
    const float* __restrict__ part, float* __restrict__ ro)
{
    int i = blockIdx.x * 256 + threadIdx.x;
    if (i >= 640) return;
    const float* pp = part + (size_t)i * 128;
    float s = 0.f;
#pragma unroll
    for (int c = 0; c < 128; ++c) s += pp[c];
    ro[i] = 0.5f * s + 0.5f;
}

__global__ __launch_bounds__(256) void readout_kernel(
    const float* __restrict__ S, const float* __restrict__ wsig,
    float* __restrict__ ro)
{
    const int tid = threadIdx.x;
    const int b = blockIdx.x >> 7;
    const int c = blockIdx.x & 127;

    __shared__ float wl[10 * 1024];
    for (int idx = tid; idx < 10240; idx += 256) {
        int o = idx >> 10;
        int f = idx & 1023;
        wl[idx] = wsig[(size_t)o * 131072 + (c << 10) + f];
    }
    __syncthreads();

    float acc[10];
#pragma unroll
    for (int o = 0; o < 10; ++o) acc[o] = 0.f;

    const float* Sp = S + ((size_t)b * COUT + c) * HWHW;
#pragma unroll
    for (int i = 0; i < 4; ++i) {
        int fl = tid + (i << 8);
        int ph = fl >> 5, pw = fl & 31;
        const float2 t0 = *(const float2*)&Sp[(ph << 7) + (pw << 1)];
        const float2 t1 = *(const float2*)&Sp[(ph << 7) + 64 + (pw << 1)];
        float m = fmaxf(fmaxf(t0.x, t0.y), fmaxf(t1.x, t1.y));
#pragma unroll
        for (int o = 0; o < 10; ++o)
            acc[o] = fmaf(m, wl[(o << 10) + fl], acc[o]);
    }

    __shared__ float psum[4][10];
    const int wave = tid >> 6;
    const int lane = tid & 63;
#pragma unroll
    for (int o = 0; o < 10; ++o) {
        float v = acc[o];
        v += __shfl_down(v, 32, 64);
        v += __shfl_down(v, 16, 64);
        v += __shfl_down(v, 8, 64);
        v += __shfl_down(v, 4, 64);
        v += __shfl_down(v, 2, 64);
        v += __shfl_down(v, 1, 64);
        if (lane == 0) psum[wave][o] = v;
    }
    __syncthreads();
    if (tid < 10) {
        float s = psum[0][tid] + psum[1][tid] + psum[2][tid] + psum[3][tid];
        atomicAdd(&ro[b * 10 + tid], 0.5f * s);
    }
}

extern "C" void kernel_launch(void* const* d_in, const int* in_sizes, int n_in,
                              void* d_out, int out_size, void* d_ws, size_t ws_size,
                              hipStream_t stream)
{
    const float* P    = (const float*)d_in[1];
    const float* Q    = (const float*)d_in[2];
    const float* R    = (const float*)d_in[3];
    const float* W    = (const float*)d_in[4];
    const float* bias = (const float*)d_in[5];
    const float* wsig = (const float*)d_in[6];
    float* out = (float*)d_out;

    const size_t wbytes      = (size_t)NW3 * 2 * 2;
    const size_t pooled_bytes = (size_t)POOLED_FLOATS * 4;
    const size_t part_bytes   = (size_t)PART_FLOATS * 4;
    const size_t pn_bytes     = (size_t)B_ * CIN * HWHW * 2;   // 33.55MB each

    const double alpha_d = exp(-1e-3 / 20e-3);
    const double oma_d   = 1.0 - alpha_d;
    const double gamma_d = exp(-1e-3 / 2.86e-3);

    // pn layout: cnt(0)|zp(256)| pooled | part | list(4MB) | pnh | pnl | w
    size_t off = 4096;
    size_t pooled_off = off; off += pooled_bytes;
    size_t part_off   = off; off += part_bytes;
    size_t list_off   = off; off += ((size_t)4 << 20);
    size_t pnh_off    = off; off += pn_bytes;
    size_t pnl_off    = off; off += pn_bytes;
    size_t w_off      = off; off += wbytes + 256;
    const int use_pn = (ws_size >= off);

    if (use_pn) {
        unsigned* cnt = (unsigned*)d_ws;
        const void* zp = (const void*)((char*)d_ws + 256);
        float* pooled = (float*)((char*)d_ws + pooled_off);
        float* part   = (float*)((char*)d_ws + part_off);
        int*   list   = (int*)((char*)d_ws + list_off);
        int    cap    = (1 << 20);
        _Float16* pnh = (_Float16*)((char*)d_ws + pnh_off);
        _Float16* pnl = (_Float16*)((char*)d_ws + pnl_off);
        _Float16* whi = (_Float16*)((char*)d_ws + w_off);
        _Float16* wlo = whi + NW3;

        (void)hipMemsetAsync(d_ws, 0, 512, stream);   // cnt + zero-page

        wprep_kernel<<<(NW3 + 255) / 256, 256, 0, stream>>>(W, whi, wlo);
        pnprep_kernel<<<dim3(64, 64), 256, 0, stream>>>(P, Q, pnh, pnl,
                                                        (float)alpha_d, (float)oma_d);

        dim3 grid(16, 2, 64);
        lif_conv_mfma_pn_kernel<<<grid, 256, 0, stream>>>(pnh, pnl, R, whi, wlo,
                                                          bias, out, pooled, zp,
                                                          cnt, list, cap,
                                                          (float)gamma_d);

        repair_list_kernel<<<2048, 256, 0, stream>>>(P, Q, R, W, bias, out,
                                                     cnt, list, cap,
                                                     alpha_d, oma_d, gamma_d);
        pool_fix_kernel<<<64, 256, 0, stream>>>(out, pooled, cnt, list, cap);
        readout_pooled_kernel<<<dim3(128, 8), 256, 0, stream>>>(pooled, wsig, part);
        readout_reduce_kernel<<<3, 256, 0, stream>>>(part, out + (size_t)2 * NPIX);
        return;
    }

    // -------- fallback path --------
    size_t wsoff = (ws_size - wbytes) & ~(size_t)63;
    _Float16* whi = (_Float16*)((char*)d_ws + wsoff);
    _Float16* wlo = whi + NW3;
    unsigned* cnt = (unsigned*)d_ws;

    const int use_pooled = ws_size >= 64 + pooled_bytes + part_bytes
                                     + (1u << 22) + wbytes + 64;
    float* pooled = use_pooled ? (float*)((char*)d_ws + 64) : (float*)d_ws;
    float* part   = use_pooled ? (float*)((char*)d_ws + 64 + pooled_bytes)
                               : (float*)d_ws;
    size_t listoff = use_pooled ? (64 + pooled_bytes + part_bytes) : 16;
    int* list = (int*)((char*)d_ws + listoff);
    size_t cap_sz = (wsoff > listoff) ? (wsoff - listoff) / 4 : 0;
    int cap = (int)(cap_sz > (size_t)NPIX ? (size_t)NPIX : cap_sz);

    (void)hipMemsetAsync(d_ws, 0, 16, stream);

    wprep_kernel<<<(NW3 + 255) / 256, 256, 0, stream>>>(W, whi, wlo);

    dim3 grid(16, 2, 64);
    lif_conv_mfma_reg_kernel<<<grid, 256, 0, stream>>>(P, Q, R, whi, wlo, bias,
                                                       out, pooled, cnt, list, cap,
                                                       use_pooled,
                                                       (float)alpha_d, (float)oma_d,
                                                       (float)gamma_d);

    repair_list_kernel<<<2048, 256, 0, stream>>>(P, Q, R, W, bias, out,
                                                 cnt, list, cap,
                                                 alpha_d, oma_d, gamma_d);

    if (use_pooled) {
        pool_fix_kernel<<<64, 256, 0, stream>>>(out, pooled, cnt, list, cap);
        readout_pooled_kernel<<<dim3(128, 8), 256, 0, stream>>>(pooled, wsig, part);
        readout_reduce_kernel<<<3, 256, 0, stream>>>(part, out + (size_t)2 * NPIX);
    } else {
        float* ro = out + (size_t)2 * NPIX;
        ro_init<<<3, 256, 0, stream>>>(ro);
        readout_kernel<<<8192, 256, 0, stream>>>(out, wsig, ro);
    }
}